// Round 8
// baseline (178.307 us; speedup 1.0000x reference)
//
#include <hip/hip_runtime.h>
#include <hip/hip_bf16.h>

static constexpr int B_ = 16, T_ = 512, E_ = 512, H_ = 8, HD_ = 64;
static constexpr int S2_ = 1023, BH_ = B_ * H_;

typedef __attribute__((ext_vector_type(4))) float f32x4;
typedef __attribute__((ext_vector_type(8))) short bf16x8;

__device__ __forceinline__ unsigned short f2b(float f) {
    union { float f; unsigned u; } v; v.f = f;
    unsigned r = (v.u + 0x7fff + ((v.u >> 16) & 1)) >> 16;
    return (unsigned short)r;
}
__device__ __forceinline__ float b2f(unsigned short b) {
    union { unsigned u; float f; } v; v.u = ((unsigned)b) << 16;
    return v.f;
}
__device__ __forceinline__ void gll16(const unsigned short* g, unsigned short* l) {
    __builtin_amdgcn_global_load_lds((const __attribute__((address_space(1))) unsigned int*)g,
                                     (__attribute__((address_space(3))) unsigned int*)l, 16, 0, 0);
}

// fp32 -> bf16 convert of x, pos_emb, Wq,Wk,Wv,Wp ; tail blocks zero p row 1023.
static constexpr long NX_ = 4194304;        // 16*512*512
static constexpr long NPE_ = 8380416;       // 16*1023*512
static constexpr long NW_ = 262144;         // 512*512
static constexpr long TOT_ = NX_ + NPE_ + 4 * NW_;   // 13623296
__global__ __launch_bounds__(256)
void convert_bf16(const float* __restrict__ x, const float* __restrict__ pe,
                  const float* __restrict__ wq, const float* __restrict__ wk,
                  const float* __restrict__ wv, const float* __restrict__ wp,
                  unsigned short* __restrict__ xb, unsigned short* __restrict__ pb,
                  unsigned short* __restrict__ wb, unsigned short* __restrict__ p)
{
    long i8 = ((long)blockIdx.x * 256 + threadIdx.x) * 8;
    if (i8 >= TOT_) {
        long idx8 = i8 - TOT_;                 // [0, 8192)
        int bh = (int)(idx8 >> 6), d = (int)(idx8 & 63);
        bf16x8 z = {};
        *reinterpret_cast<bf16x8*>(&p[((long)bh * 1024 + 1023) * 64 + d]) = z;
        return;
    }
    const float* src;
    unsigned short* dst;
    if (i8 < NX_) { src = x + i8; dst = xb + i8; }
    else if (i8 < NX_ + NPE_) { long o = i8 - NX_; src = pe + o; dst = pb + o; }
    else {
        long w = i8 - (NX_ + NPE_);
        int which = (int)(w >> 18);
        long off = w & (NW_ - 1);
        src = (which == 0 ? wq : which == 1 ? wk : which == 2 ? wv : wp) + off;
        dst = wb + ((long)which << 18) + off;
    }
    float4 a = *reinterpret_cast<const float4*>(src);
    float4 b = *reinterpret_cast<const float4*>(src + 4);
    union { bf16x8 v; unsigned short u[8]; } r;
    r.u[0] = f2b(a.x); r.u[1] = f2b(a.y); r.u[2] = f2b(a.z); r.u[3] = f2b(a.w);
    r.u[4] = f2b(b.x); r.u[5] = f2b(b.y); r.u[6] = f2b(b.z); r.u[7] = f2b(b.w);
    *reinterpret_cast<bf16x8*>(dst) = r.v;
}

// Unified projection GEMM: double-buffered global_load_lds staging with counted
// vmcnt, XOR-swizzled linear LDS, LDS-staged coalesced bf16x8 epilogue.
// blocks 0..767: QKV (mode 0/1/2), blocks 768..1279: P (mode 3).
__global__ __launch_bounds__(256)
void proj_all(const unsigned short* __restrict__ xb, const unsigned short* __restrict__ pb,
              const unsigned short* __restrict__ wb,
              const float* __restrict__ bq, const float* __restrict__ bk,
              const float* __restrict__ bv,
              const float* __restrict__ pbu, const float* __restrict__ pbv,
              unsigned short* __restrict__ qu, unsigned short* __restrict__ qv,
              unsigned short* __restrict__ kk, unsigned short* __restrict__ vT,
              unsigned short* __restrict__ pout)
{
    __shared__ __align__(16) unsigned short LDS[2][2][8192];   // [buf][A/W][128*64]
    const int tid = threadIdx.x;
    const int lane = tid & 63, w = tid >> 6;
    const int wr = w >> 1, wc = w & 1;
    const int g = lane >> 4, li = lane & 15;
    const int lr = lane >> 3;
    const int lcs = (((lane & 7) ^ (lane >> 3)) * 8);   // pre-swizzled source col

    int mode, m0, n0, M;
    const unsigned short* Ap;
    const float* bias = nullptr;
    if (blockIdx.x < 768) {
        int n = blockIdx.x;
        int xcd = n & 7, s = n >> 3;
        int gi = s / 12, c = s % 12;
        m0 = (gi * 8 + xcd) * 128;
        mode = c >> 2; n0 = (c & 3) * 128;
        Ap = xb; M = 8192;
        bias = (mode == 0) ? bq : (mode == 1) ? bk : bv;
    } else {
        int n = blockIdx.x - 768;
        int xcd = n & 7, s = n >> 3;
        int gi = s >> 2, c = s & 3;
        m0 = (gi * 8 + xcd) * 128;
        mode = 3; n0 = c * 128;
        Ap = pb; M = B_ * S2_;
    }
    const unsigned short* W = wb + ((long)mode << 18);

    auto stage = [&](int buf, int k0) {
#pragma unroll
        for (int i = 0; i < 4; ++i) {
            int c = w * 4 + i;
            int ar = m0 + c * 8 + lr; if (ar > M - 1) ar = M - 1;
            gll16(&Ap[(long)ar * 512 + k0 + lcs], &LDS[buf][0][c * 512]);
            gll16(&W[(long)(n0 + c * 8 + lr) * 512 + k0 + lcs], &LDS[buf][1][c * 512]);
        }
    };

    f32x4 acc[4][4] = {};
    stage(0, 0);
    for (int s = 0; s < 8; ++s) {
        if (s < 7) stage((s + 1) & 1, (s + 1) * 64);
        __builtin_amdgcn_sched_barrier(0);
        if (s < 7) { asm volatile("s_waitcnt vmcnt(8)" ::: "memory"); }
        else       { asm volatile("s_waitcnt vmcnt(0)" ::: "memory"); }
        __builtin_amdgcn_sched_barrier(0);
        __builtin_amdgcn_s_barrier();
        __builtin_amdgcn_sched_barrier(0);   // ds_reads must stay AFTER the barrier
        const unsigned short* As = &LDS[s & 1][0][0];
        const unsigned short* Ws = &LDS[s & 1][1][0];
#pragma unroll
        for (int ks = 0; ks < 2; ++ks) {
            bf16x8 a[4], b[4];
            const int colsw = (ks * 32 + g * 8) ^ ((li & 7) << 3);
#pragma unroll
            for (int m = 0; m < 4; ++m)
                a[m] = *reinterpret_cast<const bf16x8*>(&As[(wr * 64 + m * 16 + li) * 64 + colsw]);
#pragma unroll
            for (int nn = 0; nn < 4; ++nn)
                b[nn] = *reinterpret_cast<const bf16x8*>(&Ws[(wc * 64 + nn * 16 + li) * 64 + colsw]);
            __builtin_amdgcn_s_setprio(1);
#pragma unroll
            for (int m = 0; m < 4; ++m)
#pragma unroll
                for (int nn = 0; nn < 4; ++nn)
                    acc[m][nn] = __builtin_amdgcn_mfma_f32_16x16x32_bf16(a[m], b[nn], acc[m][nn], 0, 0, 0);
            __builtin_amdgcn_s_setprio(0);
        }
        __builtin_amdgcn_sched_barrier(0);
        __builtin_amdgcn_s_barrier();
        __builtin_amdgcn_sched_barrier(0);
    }

    // Epilogue scalars (after vmcnt(0); compiler-managed waits)
    float bias_[4] = {0.f, 0.f, 0.f, 0.f}, pu_[4] = {0.f, 0.f, 0.f, 0.f}, pv_[4] = {0.f, 0.f, 0.f, 0.f};
    if (mode != 3) {
#pragma unroll
        for (int nn = 0; nn < 4; ++nn) {
            int gn = n0 + wc * 64 + nn * 16 + li;
            bias_[nn] = bias[gn];
            if (mode == 0) { pu_[nn] = pbu[gn]; pv_[nn] = pbv[gn]; }
        }
    }

    // ---- LDS-staged coalesced epilogue: Ct is a [128][136] bf16 tile ----
    unsigned short* Ct = &LDS[0][0][0];
    const int rrow = tid >> 4, rcol = (tid & 15) * 8;

    if (mode == 2) {
        // transposed: rows = local d, cols = local t (packed 4-short writes)
#pragma unroll
        for (int m = 0; m < 4; ++m)
#pragma unroll
            for (int nn = 0; nn < 4; ++nn) {
                ushort4 pk;
                pk.x = f2b(acc[m][nn][0] + bias_[nn]);
                pk.y = f2b(acc[m][nn][1] + bias_[nn]);
                pk.z = f2b(acc[m][nn][2] + bias_[nn]);
                pk.w = f2b(acc[m][nn][3] + bias_[nn]);
                *reinterpret_cast<ushort4*>(&Ct[(wc * 64 + nn * 16 + li) * 136 + wr * 64 + m * 16 + g * 4]) = pk;
            }
        __syncthreads();
#pragma unroll
        for (int ps = 0; ps < 8; ++ps) {
            int rowd = ps * 16 + rrow;
            int gn = n0 + rowd, gm = m0 + rcol;
            int hh = gn >> 6, d = gn & 63, bb = gm >> 9, t = gm & 511;
            *reinterpret_cast<bf16x8*>(&vT[((long)(bb * 8 + hh) * 64 + d) * 512 + t]) =
                *reinterpret_cast<const bf16x8*>(&Ct[rowd * 136 + rcol]);
        }
    } else if (mode != 0) {
        // modes 1,3: row-major (bias_=0 for mode 3)
#pragma unroll
        for (int m = 0; m < 4; ++m)
#pragma unroll
            for (int nn = 0; nn < 4; ++nn)
#pragma unroll
                for (int r = 0; r < 4; ++r)
                    Ct[(wr * 64 + m * 16 + g * 4 + r) * 136 + wc * 64 + nn * 16 + li] =
                        f2b(acc[m][nn][r] + bias_[nn]);
        __syncthreads();
#pragma unroll
        for (int ps = 0; ps < 8; ++ps) {
            int row = ps * 16 + rrow;
            int gm = m0 + row, gn = n0 + rcol;
            bf16x8 v = *reinterpret_cast<const bf16x8*>(&Ct[row * 136 + rcol]);
            if (mode == 1) {
                int bb = gm >> 9, t = gm & 511, hh = gn >> 6, d = gn & 63;
                *reinterpret_cast<bf16x8*>(&kk[((long)(bb * 8 + hh) * 512 + t) * 64 + d]) = v;
            } else if (gm < M) {
                int bb = gm / 1023, j = gm - bb * 1023;
                int hh = gn >> 6, d = gn & 63;
                *reinterpret_cast<bf16x8*>(&pout[((long)(bb * 8 + hh) * 1024 + j) * 64 + d]) = v;
            }
        }
    } else {
        // mode 0: two passes (qu with pbu, qv with pbv), pre-scaled by 1/8
#pragma unroll
        for (int m = 0; m < 4; ++m)
#pragma unroll
            for (int nn = 0; nn < 4; ++nn)
#pragma unroll
                for (int r = 0; r < 4; ++r)
                    Ct[(wr * 64 + m * 16 + g * 4 + r) * 136 + wc * 64 + nn * 16 + li] =
                        f2b((acc[m][nn][r] + bias_[nn] + pu_[nn]) * 0.125f);
        __syncthreads();
#pragma unroll
        for (int ps = 0; ps < 8; ++ps) {
            int row = ps * 16 + rrow;
            int gm = m0 + row, gn = n0 + rcol;
            int bb = gm >> 9, t = gm & 511, hh = gn >> 6, d = gn & 63;
            *reinterpret_cast<bf16x8*>(&qu[((long)(bb * 8 + hh) * 512 + t) * 64 + d]) =
                *reinterpret_cast<const bf16x8*>(&Ct[row * 136 + rcol]);
        }
        __syncthreads();
#pragma unroll
        for (int m = 0; m < 4; ++m)
#pragma unroll
            for (int nn = 0; nn < 4; ++nn)
#pragma unroll
                for (int r = 0; r < 4; ++r)
                    Ct[(wr * 64 + m * 16 + g * 4 + r) * 136 + wc * 64 + nn * 16 + li] =
                        f2b((acc[m][nn][r] + bias_[nn] + pv_[nn]) * 0.125f);
        __syncthreads();
#pragma unroll
        for (int ps = 0; ps < 8; ++ps) {
            int row = ps * 16 + rrow;
            int gm = m0 + row, gn = n0 + rcol;
            int bb = gm >> 9, t = gm & 511, hh = gn >> 6, d = gn & 63;
            *reinterpret_cast<bf16x8*>(&qv[((long)(bb * 8 + hh) * 512 + t) * 64 + d]) =
                *reinterpret_cast<const bf16x8*>(&Ct[row * 136 + rcol]);
        }
    }
}

// Fused attention v3: NO LDS staging (K/V/p read direct from global -> L2-hit),
// no block barriers at all; BD diagonal gather via ds_bpermute (__shfl);
// per-wave LDS strip only for the P transpose. No-max softmax (scores small).
__global__ __launch_bounds__(256)
void attn_fused(const unsigned short* __restrict__ qu, const unsigned short* __restrict__ qv,
                const unsigned short* __restrict__ kk, const unsigned short* __restrict__ vT,
                const unsigned short* __restrict__ p, float* __restrict__ out)
{
    __shared__ unsigned short UN[4][16][72];   // per-wave P-transpose strip
    const int tid = threadIdx.x, lane = tid & 63, w = tid >> 6;
    const int g = lane >> 4, li = lane & 15;
    const int n = blockIdx.x;            // 0..1023, XCD-swizzled
    const int xcd = n & 7, rr = n >> 3;
    const int j = rr & 15, ti = rr >> 4;
    const int bh = xcd * 16 + j;
    const int bb = bh >> 3, hh = bh & 7;
    const int t0 = ti * 64;
    const int wo = 48 - w * 16;

    bf16x8 aq[2], av[2];
    const int trow = t0 + w * 16 + li;
#pragma unroll
    for (int ks = 0; ks < 2; ++ks) {
        aq[ks] = *reinterpret_cast<const bf16x8*>(&qu[((long)bh * 512 + trow) * 64 + ks * 32 + g * 8]);
        av[ks] = *reinterpret_cast<const bf16x8*>(&qv[((long)bh * 512 + trow) * 64 + ks * 32 + g * 8]);
    }

    const unsigned short* kbase = kk + (long)bh * 512 * 64;
    const unsigned short* vbase = vT + (long)bh * 64 * 512;
    const unsigned short* pbase = p  + (long)bh * 1024 * 64;
    const int pw0 = 448 - t0 + wo;       // p-window base row at s0=0 for this wave

    f32x4 O[4] = {};
    float lrow[4] = {0.f, 0.f, 0.f, 0.f};

    for (int s0 = 0; s0 < 512; s0 += 64) {
        // QK^T + BD, B-fragments straight from global (L2)
        f32x4 S[4] = {};
        f32x4 bd[5] = {};
#pragma unroll
        for (int ks = 0; ks < 2; ++ks) {
            const int kc = ks * 32 + g * 8;
#pragma unroll
            for (int f = 0; f < 4; ++f) {
                bf16x8 bf = *reinterpret_cast<const bf16x8*>(&kbase[(long)(s0 + f * 16 + li) * 64 + kc]);
                S[f] = __builtin_amdgcn_mfma_f32_16x16x32_bf16(aq[ks], bf, S[f], 0, 0, 0);
            }
#pragma unroll
            for (int fb = 0; fb < 5; ++fb) {
                bf16x8 bf = *reinterpret_cast<const bf16x8*>(&pbase[(long)(pw0 + s0 + fb * 16 + li) * 64 + kc]);
                bd[fb] = __builtin_amdgcn_mfma_f32_16x16x32_bf16(av[ks], bf, bd[fb], 0, 0, 0);
            }
        }
        // diagonal rel-shift gather in-register: S[t,s] += BD[t, s-t+15]
        // (bpermute within the 16-lane group; row tt=g*4+r, shift s=15-tt)
#pragma unroll
        for (int r = 0; r < 4; ++r) {
            const int tt = g * 4 + r;
            const int sh = 15 - tt;
            const int srcl = (lane & 48) | ((li + sh) & 15);
            const bool wrap = (li + sh) >= 16;
            float sv[5];
#pragma unroll
            for (int q = 0; q < 5; ++q) sv[q] = __shfl(bd[q][r], srcl, 64);
#pragma unroll
            for (int f = 0; f < 4; ++f) {
                float pv = __expf(S[f][r] + (wrap ? sv[f + 1] : sv[f]));
                S[f][r] = pv;
                lrow[r] += pv;
            }
        }
        // P -> per-wave LDS strip (transpose to A-fragment layout)
#pragma unroll
        for (int f = 0; f < 4; ++f)
#pragma unroll
            for (int r = 0; r < 4; ++r)
                UN[w][g * 4 + r][f * 16 + li] = f2b(S[f][r]);
        // PV (V B-fragments straight from global)
        __builtin_amdgcn_s_setprio(1);
#pragma unroll
        for (int ks = 0; ks < 2; ++ks) {
            bf16x8 pa = *reinterpret_cast<const bf16x8*>(&UN[w][li][ks * 32 + g * 8]);
#pragma unroll
            for (int fd = 0; fd < 4; ++fd) {
                bf16x8 vb = *reinterpret_cast<const bf16x8*>(&vbase[(long)(fd * 16 + li) * 512 + s0 + ks * 32 + g * 8]);
                O[fd] = __builtin_amdgcn_mfma_f32_16x16x32_bf16(pa, vb, O[fd], 0, 0, 0);
            }
        }
        __builtin_amdgcn_s_setprio(0);
    }
    // final row-sum reduce across the 16 lanes of each group
#pragma unroll
    for (int r = 0; r < 4; ++r) {
#pragma unroll
        for (int msk = 1; msk < 16; msk <<= 1)
            lrow[r] += __shfl_xor(lrow[r], msk);
    }
#pragma unroll
    for (int fd = 0; fd < 4; ++fd) {
#pragma unroll
        for (int r = 0; r < 4; ++r) {
            int t = t0 + w * 16 + g * 4 + r;
            int d = fd * 16 + li;
            out[((long)(bb * 512 + t)) * 512 + hh * 64 + d] = O[fd][r] / lrow[r];
        }
    }
}

extern "C" void kernel_launch(void* const* d_in, const int* in_sizes, int n_in,
                              void* d_out, int out_size, void* d_ws, size_t ws_size,
                              hipStream_t stream)
{
    const float* x   = (const float*)d_in[0];
    const float* pe  = (const float*)d_in[1];
    const float* Wq  = (const float*)d_in[2];
    const float* bq  = (const float*)d_in[3];
    const float* Wk  = (const float*)d_in[4];
    const float* bk  = (const float*)d_in[5];
    const float* Wv  = (const float*)d_in[6];
    const float* bv  = (const float*)d_in[7];
    const float* Wp  = (const float*)d_in[8];
    const float* pbu = (const float*)d_in[9];
    const float* pbv = (const float*)d_in[10];
    float* out = (float*)d_out;

    unsigned short* qu = (unsigned short*)d_ws;                  // [BH][512][64]
    unsigned short* qv = qu + (size_t)BH_ * 512 * 64;
    unsigned short* kk = qv + (size_t)BH_ * 512 * 64;
    unsigned short* vT = kk + (size_t)BH_ * 512 * 64;            // [BH][64][512]
    unsigned short* p  = vT + (size_t)BH_ * 512 * 64;            // [BH][1024][64]
    unsigned short* xb = p  + (size_t)BH_ * 1024 * 64;           // [8192][512]
    unsigned short* pb = xb + (size_t)NX_;                       // [16*1023][512]
    unsigned short* wb = pb + (size_t)NPE_;                      // [4*512][512]

    dim3 blk(256);
    convert_bf16<<<dim3(6656), blk, 0, stream>>>(x, pe, Wq, Wk, Wv, Wp, xb, pb, wb, p);
    proj_all<<<dim3(1280), blk, 0, stream>>>(xb, pb, wb, bq, bk, bv, pbu, pbv, qu, qv, kk, vT, p);
    attn_fused<<<dim3(1024), blk, 0, stream>>>(qu, qv, kk, vT, p, out);
}

// Round 9
// 85.938 us; speedup vs baseline: 2.0748x; 2.0748x over previous
//
#include <hip/hip_runtime.h>
#include <hip/hip_bf16.h>

static constexpr int B_ = 16, T_ = 512, E_ = 512, H_ = 8, HD_ = 64;
static constexpr int S2_ = 1023, BH_ = B_ * H_;

typedef __attribute__((ext_vector_type(4))) float f32x4;
typedef __attribute__((ext_vector_type(8))) short bf16x8;

__device__ __forceinline__ unsigned short f2b(float f) {
    union { float f; unsigned u; } v; v.f = f;
    unsigned r = (v.u + 0x7fff + ((v.u >> 16) & 1)) >> 16;
    return (unsigned short)r;
}
__device__ __forceinline__ float b2f(unsigned short b) {
    union { unsigned u; float f; } v; v.u = ((unsigned)b) << 16;
    return v.f;
}
__device__ __forceinline__ void gll16(const unsigned short* g, unsigned short* l) {
    __builtin_amdgcn_global_load_lds((const __attribute__((address_space(1))) unsigned int*)g,
                                     (__attribute__((address_space(3))) unsigned int*)l, 16, 0, 0);
}

// fp32 -> bf16 convert of x, pos_emb, Wq,Wk,Wv,Wp ; tail blocks zero p row 1023.
static constexpr long NX_ = 4194304;        // 16*512*512
static constexpr long NPE_ = 8380416;       // 16*1023*512
static constexpr long NW_ = 262144;         // 512*512
static constexpr long TOT_ = NX_ + NPE_ + 4 * NW_;   // 13623296
__global__ __launch_bounds__(256)
void convert_bf16(const float* __restrict__ x, const float* __restrict__ pe,
                  const float* __restrict__ wq, const float* __restrict__ wk,
                  const float* __restrict__ wv, const float* __restrict__ wp,
                  unsigned short* __restrict__ xb, unsigned short* __restrict__ pb,
                  unsigned short* __restrict__ wb, unsigned short* __restrict__ p)
{
    long i8 = ((long)blockIdx.x * 256 + threadIdx.x) * 8;
    if (i8 >= TOT_) {
        long idx8 = i8 - TOT_;                 // [0, 8192)
        int bh = (int)(idx8 >> 6), d = (int)(idx8 & 63);
        bf16x8 z = {};
        *reinterpret_cast<bf16x8*>(&p[((long)bh * 1024 + 1023) * 64 + d]) = z;
        return;
    }
    const float* src;
    unsigned short* dst;
    if (i8 < NX_) { src = x + i8; dst = xb + i8; }
    else if (i8 < NX_ + NPE_) { long o = i8 - NX_; src = pe + o; dst = pb + o; }
    else {
        long w = i8 - (NX_ + NPE_);
        int which = (int)(w >> 18);
        long off = w & (NW_ - 1);
        src = (which == 0 ? wq : which == 1 ? wk : which == 2 ? wv : wp) + off;
        dst = wb + ((long)which << 18) + off;
    }
    float4 a = *reinterpret_cast<const float4*>(src);
    float4 b = *reinterpret_cast<const float4*>(src + 4);
    union { bf16x8 v; unsigned short u[8]; } r;
    r.u[0] = f2b(a.x); r.u[1] = f2b(a.y); r.u[2] = f2b(a.z); r.u[3] = f2b(a.w);
    r.u[4] = f2b(b.x); r.u[5] = f2b(b.y); r.u[6] = f2b(b.z); r.u[7] = f2b(b.w);
    *reinterpret_cast<bf16x8*>(dst) = r.v;
}

// Unified projection GEMM: double-buffered global_load_lds staging with counted
// vmcnt, XOR-swizzled linear LDS, LDS-staged coalesced bf16x8 epilogue.
// blocks 0..767: QKV (mode 0/1/2), blocks 768..1279: P (mode 3).
// qu/qv carry 0.125*log2(e) so attention softmax can use native exp2.
__global__ __launch_bounds__(256)
void proj_all(const unsigned short* __restrict__ xb, const unsigned short* __restrict__ pb,
              const unsigned short* __restrict__ wb,
              const float* __restrict__ bq, const float* __restrict__ bk,
              const float* __restrict__ bv,
              const float* __restrict__ pbu, const float* __restrict__ pbv,
              unsigned short* __restrict__ qu, unsigned short* __restrict__ qv,
              unsigned short* __restrict__ kk, unsigned short* __restrict__ vT,
              unsigned short* __restrict__ pout)
{
    __shared__ __align__(16) unsigned short LDS[2][2][8192];   // [buf][A/W][128*64]
    const int tid = threadIdx.x;
    const int lane = tid & 63, w = tid >> 6;
    const int wr = w >> 1, wc = w & 1;
    const int g = lane >> 4, li = lane & 15;
    const int lr = lane >> 3;
    const int lcs = (((lane & 7) ^ (lane >> 3)) * 8);   // pre-swizzled source col

    int mode, m0, n0, M;
    const unsigned short* Ap;
    const float* bias = nullptr;
    if (blockIdx.x < 768) {
        int n = blockIdx.x;
        int xcd = n & 7, s = n >> 3;
        int gi = s / 12, c = s % 12;
        m0 = (gi * 8 + xcd) * 128;
        mode = c >> 2; n0 = (c & 3) * 128;
        Ap = xb; M = 8192;
        bias = (mode == 0) ? bq : (mode == 1) ? bk : bv;
    } else {
        int n = blockIdx.x - 768;
        int xcd = n & 7, s = n >> 3;
        int gi = s >> 2, c = s & 3;
        m0 = (gi * 8 + xcd) * 128;
        mode = 3; n0 = c * 128;
        Ap = pb; M = B_ * S2_;
    }
    const unsigned short* W = wb + ((long)mode << 18);

    auto stage = [&](int buf, int k0) {
#pragma unroll
        for (int i = 0; i < 4; ++i) {
            int c = w * 4 + i;
            int ar = m0 + c * 8 + lr; if (ar > M - 1) ar = M - 1;
            gll16(&Ap[(long)ar * 512 + k0 + lcs], &LDS[buf][0][c * 512]);
            gll16(&W[(long)(n0 + c * 8 + lr) * 512 + k0 + lcs], &LDS[buf][1][c * 512]);
        }
    };

    f32x4 acc[4][4] = {};
    stage(0, 0);
    for (int s = 0; s < 8; ++s) {
        if (s < 7) stage((s + 1) & 1, (s + 1) * 64);
        __builtin_amdgcn_sched_barrier(0);
        if (s < 7) { asm volatile("s_waitcnt vmcnt(8)" ::: "memory"); }
        else       { asm volatile("s_waitcnt vmcnt(0)" ::: "memory"); }
        __builtin_amdgcn_sched_barrier(0);
        __builtin_amdgcn_s_barrier();
        __builtin_amdgcn_sched_barrier(0);   // ds_reads must stay AFTER the barrier
        const unsigned short* As = &LDS[s & 1][0][0];
        const unsigned short* Ws = &LDS[s & 1][1][0];
#pragma unroll
        for (int ks = 0; ks < 2; ++ks) {
            bf16x8 a[4], b[4];
            const int colsw = (ks * 32 + g * 8) ^ ((li & 7) << 3);
#pragma unroll
            for (int m = 0; m < 4; ++m)
                a[m] = *reinterpret_cast<const bf16x8*>(&As[(wr * 64 + m * 16 + li) * 64 + colsw]);
#pragma unroll
            for (int nn = 0; nn < 4; ++nn)
                b[nn] = *reinterpret_cast<const bf16x8*>(&Ws[(wc * 64 + nn * 16 + li) * 64 + colsw]);
            __builtin_amdgcn_s_setprio(1);
#pragma unroll
            for (int m = 0; m < 4; ++m)
#pragma unroll
                for (int nn = 0; nn < 4; ++nn)
                    acc[m][nn] = __builtin_amdgcn_mfma_f32_16x16x32_bf16(a[m], b[nn], acc[m][nn], 0, 0, 0);
            __builtin_amdgcn_s_setprio(0);
        }
        __builtin_amdgcn_sched_barrier(0);
        __builtin_amdgcn_s_barrier();
        __builtin_amdgcn_sched_barrier(0);
    }

    // Epilogue scalars (after vmcnt(0); compiler-managed waits)
    float bias_[4] = {0.f, 0.f, 0.f, 0.f}, pu_[4] = {0.f, 0.f, 0.f, 0.f}, pv_[4] = {0.f, 0.f, 0.f, 0.f};
    if (mode != 3) {
#pragma unroll
        for (int nn = 0; nn < 4; ++nn) {
            int gn = n0 + wc * 64 + nn * 16 + li;
            bias_[nn] = bias[gn];
            if (mode == 0) { pu_[nn] = pbu[gn]; pv_[nn] = pbv[gn]; }
        }
    }

    // ---- LDS-staged coalesced epilogue: Ct is a [128][136] bf16 tile ----
    unsigned short* Ct = &LDS[0][0][0];
    const int rrow = tid >> 4, rcol = (tid & 15) * 8;
    const float QS = 0.125f * 1.4426950408889634f;   // 1/8 * log2(e)

    if (mode == 2) {
        // transposed: rows = local d, cols = local t (packed 4-short writes)
#pragma unroll
        for (int m = 0; m < 4; ++m)
#pragma unroll
            for (int nn = 0; nn < 4; ++nn) {
                ushort4 pk;
                pk.x = f2b(acc[m][nn][0] + bias_[nn]);
                pk.y = f2b(acc[m][nn][1] + bias_[nn]);
                pk.z = f2b(acc[m][nn][2] + bias_[nn]);
                pk.w = f2b(acc[m][nn][3] + bias_[nn]);
                *reinterpret_cast<ushort4*>(&Ct[(wc * 64 + nn * 16 + li) * 136 + wr * 64 + m * 16 + g * 4]) = pk;
            }
        __syncthreads();
#pragma unroll
        for (int ps = 0; ps < 8; ++ps) {
            int rowd = ps * 16 + rrow;
            int gn = n0 + rowd, gm = m0 + rcol;
            int hh = gn >> 6, d = gn & 63, bb = gm >> 9, t = gm & 511;
            *reinterpret_cast<bf16x8*>(&vT[((long)(bb * 8 + hh) * 64 + d) * 512 + t]) =
                *reinterpret_cast<const bf16x8*>(&Ct[rowd * 136 + rcol]);
        }
    } else if (mode != 0) {
        // modes 1,3: row-major (bias_=0 for mode 3)
#pragma unroll
        for (int m = 0; m < 4; ++m)
#pragma unroll
            for (int nn = 0; nn < 4; ++nn)
#pragma unroll
                for (int r = 0; r < 4; ++r)
                    Ct[(wr * 64 + m * 16 + g * 4 + r) * 136 + wc * 64 + nn * 16 + li] =
                        f2b(acc[m][nn][r] + bias_[nn]);
        __syncthreads();
#pragma unroll
        for (int ps = 0; ps < 8; ++ps) {
            int row = ps * 16 + rrow;
            int gm = m0 + row, gn = n0 + rcol;
            bf16x8 v = *reinterpret_cast<const bf16x8*>(&Ct[row * 136 + rcol]);
            if (mode == 1) {
                int bb = gm >> 9, t = gm & 511, hh = gn >> 6, d = gn & 63;
                *reinterpret_cast<bf16x8*>(&kk[((long)(bb * 8 + hh) * 512 + t) * 64 + d]) = v;
            } else if (gm < M) {
                int bb = gm / 1023, j = gm - bb * 1023;
                int hh = gn >> 6, d = gn & 63;
                *reinterpret_cast<bf16x8*>(&pout[((long)(bb * 8 + hh) * 1024 + j) * 64 + d]) = v;
            }
        }
    } else {
        // mode 0: two passes (qu with pbu, qv with pbv), pre-scaled by QS
#pragma unroll
        for (int m = 0; m < 4; ++m)
#pragma unroll
            for (int nn = 0; nn < 4; ++nn)
#pragma unroll
                for (int r = 0; r < 4; ++r)
                    Ct[(wr * 64 + m * 16 + g * 4 + r) * 136 + wc * 64 + nn * 16 + li] =
                        f2b((acc[m][nn][r] + bias_[nn] + pu_[nn]) * QS);
        __syncthreads();
#pragma unroll
        for (int ps = 0; ps < 8; ++ps) {
            int row = ps * 16 + rrow;
            int gm = m0 + row, gn = n0 + rcol;
            int bb = gm >> 9, t = gm & 511, hh = gn >> 6, d = gn & 63;
            *reinterpret_cast<bf16x8*>(&qu[((long)(bb * 8 + hh) * 512 + t) * 64 + d]) =
                *reinterpret_cast<const bf16x8*>(&Ct[row * 136 + rcol]);
        }
        __syncthreads();
#pragma unroll
        for (int m = 0; m < 4; ++m)
#pragma unroll
            for (int nn = 0; nn < 4; ++nn)
#pragma unroll
                for (int r = 0; r < 4; ++r)
                    Ct[(wr * 64 + m * 16 + g * 4 + r) * 136 + wc * 64 + nn * 16 + li] =
                        f2b((acc[m][nn][r] + bias_[nn] + pv_[nn]) * QS);
        __syncthreads();
#pragma unroll
        for (int ps = 0; ps < 8; ++ps) {
            int row = ps * 16 + rrow;
            int gm = m0 + row, gn = n0 + rcol;
            int bb = gm >> 9, t = gm & 511, hh = gn >> 6, d = gn & 63;
            *reinterpret_cast<bf16x8*>(&qv[((long)(bb * 8 + hh) * 512 + t) * 64 + d]) =
                *reinterpret_cast<const bf16x8*>(&Ct[row * 136 + rcol]);
        }
    }
}

// Fused attention v4: r7 staged structure + in-register shfl diagonal gather
// (no BD stash), exp2 softmax (scale folded upstream), all-swizzled 40960B LDS
// (4 blocks/CU). No-max softmax (scores provably small), deferred sum reduce.
__global__ __launch_bounds__(256)
void attn_fused(const unsigned short* __restrict__ qu, const unsigned short* __restrict__ qv,
                const unsigned short* __restrict__ kk, const unsigned short* __restrict__ vT,
                const unsigned short* __restrict__ p, float* __restrict__ out)
{
    __shared__ unsigned short Ks[64][64];    // XOR-swizzled: col ^ ((row&7)<<3)
    __shared__ unsigned short Vs[64][64];
    __shared__ unsigned short Pw[128][64];
    __shared__ unsigned short UN[4][16][64]; // per-wave P strip, swizzled
    const int tid = threadIdx.x, lane = tid & 63, w = tid >> 6;
    const int g = lane >> 4, li = lane & 15;
    const int n = blockIdx.x;            // 0..1023, XCD-swizzled
    const int xcd = n & 7, rr = n >> 3;
    const int j = rr & 15, ti = rr >> 4;
    const int bh = xcd * 16 + j;
    const int bb = bh >> 3, hh = bh & 7;
    const int t0 = ti * 64;
    const int wo = 48 - w * 16;

    bf16x8 aq[2], av[2];
    const int trow = t0 + w * 16 + li;
#pragma unroll
    for (int ks = 0; ks < 2; ++ks) {
        aq[ks] = *reinterpret_cast<const bf16x8*>(&qu[((long)bh * 512 + trow) * 64 + ks * 32 + g * 8]);
        av[ks] = *reinterpret_cast<const bf16x8*>(&qv[((long)bh * 512 + trow) * 64 + ks * 32 + g * 8]);
    }

    bf16x8 kreg[2], vreg[2], preg[4];
    const int srow = tid >> 3, scol8 = (tid & 7) * 8;
    const int scolsw = scol8 ^ ((srow & 7) << 3);        // swizzled LDS col
    auto load_tile = [&](int s0) {
        const int pwb = 448 + s0 - t0;
#pragma unroll
        for (int i = 0; i < 2; ++i) {
            int row = srow + i * 32;
            kreg[i] = *reinterpret_cast<const bf16x8*>(&kk[((long)bh * 512 + s0 + row) * 64 + scol8]);
            vreg[i] = *reinterpret_cast<const bf16x8*>(&vT[((long)bh * 64 + row) * 512 + s0 + scol8]);
        }
#pragma unroll
        for (int i = 0; i < 4; ++i) {
            int row = srow + i * 32;
            preg[i] = *reinterpret_cast<const bf16x8*>(&p[((long)bh * 1024 + pwb + row) * 64 + scol8]);
        }
    };

    f32x4 O[4] = {};
    float lrow[4] = {0.f, 0.f, 0.f, 0.f};

    load_tile(0);
    for (int s0 = 0; s0 < 512; s0 += 64) {
#pragma unroll
        for (int i = 0; i < 2; ++i) {
            int row = srow + i * 32;
            *reinterpret_cast<bf16x8*>(&Ks[row][scolsw]) = kreg[i];
            *reinterpret_cast<bf16x8*>(&Vs[row][scolsw]) = vreg[i];
        }
#pragma unroll
        for (int i = 0; i < 4; ++i) {
            int row = srow + i * 32;
            *reinterpret_cast<bf16x8*>(&Pw[row][scolsw]) = preg[i];
        }
        __syncthreads();
        if (s0 < 448) load_tile(s0 + 64);   // prefetch next tile into regs

        // QK^T + BD (B-fragments from swizzled LDS)
        f32x4 S[4] = {};
        f32x4 bd[5] = {};
        __builtin_amdgcn_s_setprio(1);
#pragma unroll
        for (int ks = 0; ks < 2; ++ks) {
            const int colsw = (ks * 32 + g * 8) ^ ((li & 7) << 3);
#pragma unroll
            for (int f = 0; f < 4; ++f) {
                bf16x8 bf = *reinterpret_cast<const bf16x8*>(&Ks[f * 16 + li][colsw]);
                S[f] = __builtin_amdgcn_mfma_f32_16x16x32_bf16(aq[ks], bf, S[f], 0, 0, 0);
            }
#pragma unroll
            for (int fb = 0; fb < 5; ++fb) {
                bf16x8 bf = *reinterpret_cast<const bf16x8*>(&Pw[wo + fb * 16 + li][colsw]);
                bd[fb] = __builtin_amdgcn_mfma_f32_16x16x32_bf16(av[ks], bf, bd[fb], 0, 0, 0);
            }
        }
        __builtin_amdgcn_s_setprio(0);
        // diagonal rel-shift gather in-register: S[t,s] += BD[t, s-t+15]
#pragma unroll
        for (int r = 0; r < 4; ++r) {
            const int tt = g * 4 + r;
            const int sh = 15 - tt;
            const int srcl = (lane & 48) | ((li + sh) & 15);
            const bool wrap = (li + sh) >= 16;
            float sv[5];
#pragma unroll
            for (int q = 0; q < 5; ++q) sv[q] = __shfl(bd[q][r], srcl, 64);
#pragma unroll
            for (int f = 0; f < 4; ++f) {
                float pv = __builtin_exp2f(S[f][r] + (wrap ? sv[f + 1] : sv[f]));
                S[f][r] = pv;
                lrow[r] += pv;
            }
        }
        // P -> per-wave LDS strip (swizzled transpose to A-fragment layout)
#pragma unroll
        for (int f = 0; f < 4; ++f)
#pragma unroll
            for (int r = 0; r < 4; ++r) {
                int tt = g * 4 + r;
                UN[w][tt][(f * 16 + li) ^ ((tt & 7) << 3)] = f2b(S[f][r]);
            }
        // PV
        __builtin_amdgcn_s_setprio(1);
#pragma unroll
        for (int ks = 0; ks < 2; ++ks) {
            const int colsw = (ks * 32 + g * 8) ^ ((li & 7) << 3);
            bf16x8 pa = *reinterpret_cast<const bf16x8*>(&UN[w][li][colsw]);
#pragma unroll
            for (int fd = 0; fd < 4; ++fd) {
                bf16x8 vb = *reinterpret_cast<const bf16x8*>(&Vs[fd * 16 + li][colsw]);
                O[fd] = __builtin_amdgcn_mfma_f32_16x16x32_bf16(pa, vb, O[fd], 0, 0, 0);
            }
        }
        __builtin_amdgcn_s_setprio(0);
        __syncthreads();
    }
    // final row-sum reduce across the 16 lanes of each group
#pragma unroll
    for (int r = 0; r < 4; ++r) {
#pragma unroll
        for (int msk = 1; msk < 16; msk <<= 1)
            lrow[r] += __shfl_xor(lrow[r], msk);
    }
#pragma unroll
    for (int fd = 0; fd < 4; ++fd) {
#pragma unroll
        for (int r = 0; r < 4; ++r) {
            int t = t0 + w * 16 + g * 4 + r;
            int d = fd * 16 + li;
            out[((long)(bb * 512 + t)) * 512 + hh * 64 + d] = O[fd][r] / lrow[r];
        }
    }
}

extern "C" void kernel_launch(void* const* d_in, const int* in_sizes, int n_in,
                              void* d_out, int out_size, void* d_ws, size_t ws_size,
                              hipStream_t stream)
{
    const float* x   = (const float*)d_in[0];
    const float* pe  = (const float*)d_in[1];
    const float* Wq  = (const float*)d_in[2];
    const float* bq  = (const float*)d_in[3];
    const float* Wk  = (const float*)d_in[4];
    const float* bk  = (const float*)d_in[5];
    const float* Wv  = (const float*)d_in[6];
    const float* bv  = (const float*)d_in[7];
    const float* Wp  = (const float*)d_in[8];
    const float* pbu = (const float*)d_in[9];
    const float* pbv = (const float*)d_in[10];
    float* out = (float*)d_out;

    unsigned short* qu = (unsigned short*)d_ws;                  // [BH][512][64]
    unsigned short* qv = qu + (size_t)BH_ * 512 * 64;
    unsigned short* kk = qv + (size_t)BH_ * 512 * 64;
    unsigned short* vT = kk + (size_t)BH_ * 512 * 64;            // [BH][64][512]
    unsigned short* p  = vT + (size_t)BH_ * 512 * 64;            // [BH][1024][64]
    unsigned short* xb = p  + (size_t)BH_ * 1024 * 64;           // [8192][512]
    unsigned short* pb = xb + (size_t)NX_;                       // [16*1023][512]
    unsigned short* wb = pb + (size_t)NPE_;                      // [4*512][512]

    dim3 blk(256);
    convert_bf16<<<dim3(6656), blk, 0, stream>>>(x, pe, Wq, Wk, Wv, Wp, xb, pb, wb, p);
    proj_all<<<dim3(1280), blk, 0, stream>>>(xb, pb, wb, bq, bk, bv, pbu, pbv, qu, qv, kk, vT, p);
    attn_fused<<<dim3(1024), blk, 0, stream>>>(qu, qv, kk, vT, p, out);
}

// Round 10
// 83.546 us; speedup vs baseline: 2.1342x; 1.0286x over previous
//
#include <hip/hip_runtime.h>
#include <hip/hip_bf16.h>

static constexpr int B_ = 16, T_ = 512, E_ = 512, H_ = 8, HD_ = 64;
static constexpr int S2_ = 1023, BH_ = B_ * H_;

typedef __attribute__((ext_vector_type(4))) float f32x4;
typedef __attribute__((ext_vector_type(8))) short bf16x8;

__device__ __forceinline__ unsigned short f2b(float f) {
    union { float f; unsigned u; } v; v.f = f;
    unsigned r = (v.u + 0x7fff + ((v.u >> 16) & 1)) >> 16;
    return (unsigned short)r;
}
__device__ __forceinline__ float b2f(unsigned short b) {
    union { unsigned u; float f; } v; v.u = ((unsigned)b) << 16;
    return v.f;
}
__device__ __forceinline__ void gll16(const unsigned short* g, unsigned short* l) {
    __builtin_amdgcn_global_load_lds((const __attribute__((address_space(1))) unsigned int*)g,
                                     (__attribute__((address_space(3))) unsigned int*)l, 16, 0, 0);
}

// fp32 -> bf16 convert of x, pos_emb, Wq,Wk,Wv,Wp ; tail blocks zero p row 1023.
static constexpr long NX_ = 4194304;        // 16*512*512
static constexpr long NPE_ = 8380416;       // 16*1023*512
static constexpr long NW_ = 262144;         // 512*512
static constexpr long TOT_ = NX_ + NPE_ + 4 * NW_;   // 13623296
__global__ __launch_bounds__(256)
void convert_bf16(const float* __restrict__ x, const float* __restrict__ pe,
                  const float* __restrict__ wq, const float* __restrict__ wk,
                  const float* __restrict__ wv, const float* __restrict__ wp,
                  unsigned short* __restrict__ xb, unsigned short* __restrict__ pb,
                  unsigned short* __restrict__ wb, unsigned short* __restrict__ p)
{
    long i8 = ((long)blockIdx.x * 256 + threadIdx.x) * 8;
    if (i8 >= TOT_) {
        long idx8 = i8 - TOT_;                 // [0, 8192)
        int bh = (int)(idx8 >> 6), d = (int)(idx8 & 63);
        bf16x8 z = {};
        *reinterpret_cast<bf16x8*>(&p[((long)bh * 1024 + 1023) * 64 + d]) = z;
        return;
    }
    const float* src;
    unsigned short* dst;
    if (i8 < NX_) { src = x + i8; dst = xb + i8; }
    else if (i8 < NX_ + NPE_) { long o = i8 - NX_; src = pe + o; dst = pb + o; }
    else {
        long w = i8 - (NX_ + NPE_);
        int which = (int)(w >> 18);
        long off = w & (NW_ - 1);
        src = (which == 0 ? wq : which == 1 ? wk : which == 2 ? wv : wp) + off;
        dst = wb + ((long)which << 18) + off;
    }
    float4 a = *reinterpret_cast<const float4*>(src);
    float4 b = *reinterpret_cast<const float4*>(src + 4);
    union { bf16x8 v; unsigned short u[8]; } r;
    r.u[0] = f2b(a.x); r.u[1] = f2b(a.y); r.u[2] = f2b(a.z); r.u[3] = f2b(a.w);
    r.u[4] = f2b(b.x); r.u[5] = f2b(b.y); r.u[6] = f2b(b.z); r.u[7] = f2b(b.w);
    *reinterpret_cast<bf16x8*>(dst) = r.v;
}

// Unified projection GEMM: double-buffered global_load_lds staging with counted
// vmcnt, XOR-swizzled linear LDS, LDS-staged coalesced bf16x8 epilogue.
// blocks 0..767: QKV (mode 0/1/2), blocks 768..1279: P (mode 3).
// qu/qv carry 0.125*log2(e) so attention softmax can use native exp2.
__global__ __launch_bounds__(256)
void proj_all(const unsigned short* __restrict__ xb, const unsigned short* __restrict__ pb,
              const unsigned short* __restrict__ wb,
              const float* __restrict__ bq, const float* __restrict__ bk,
              const float* __restrict__ bv,
              const float* __restrict__ pbu, const float* __restrict__ pbv,
              unsigned short* __restrict__ qu, unsigned short* __restrict__ qv,
              unsigned short* __restrict__ kk, unsigned short* __restrict__ vT,
              unsigned short* __restrict__ pout)
{
    __shared__ __align__(16) unsigned short LDS[2][2][8192];   // [buf][A/W][128*64]
    const int tid = threadIdx.x;
    const int lane = tid & 63, w = tid >> 6;
    const int wr = w >> 1, wc = w & 1;
    const int g = lane >> 4, li = lane & 15;
    const int lr = lane >> 3;
    const int lcs = (((lane & 7) ^ (lane >> 3)) * 8);   // pre-swizzled source col

    int mode, m0, n0, M;
    const unsigned short* Ap;
    const float* bias = nullptr;
    if (blockIdx.x < 768) {
        int n = blockIdx.x;
        int xcd = n & 7, s = n >> 3;
        int gi = s / 12, c = s % 12;
        m0 = (gi * 8 + xcd) * 128;
        mode = c >> 2; n0 = (c & 3) * 128;
        Ap = xb; M = 8192;
        bias = (mode == 0) ? bq : (mode == 1) ? bk : bv;
    } else {
        int n = blockIdx.x - 768;
        int xcd = n & 7, s = n >> 3;
        int gi = s >> 2, c = s & 3;
        m0 = (gi * 8 + xcd) * 128;
        mode = 3; n0 = c * 128;
        Ap = pb; M = B_ * S2_;
    }
    const unsigned short* W = wb + ((long)mode << 18);

    auto stage = [&](int buf, int k0) {
#pragma unroll
        for (int i = 0; i < 4; ++i) {
            int c = w * 4 + i;
            int ar = m0 + c * 8 + lr; if (ar > M - 1) ar = M - 1;
            gll16(&Ap[(long)ar * 512 + k0 + lcs], &LDS[buf][0][c * 512]);
            gll16(&W[(long)(n0 + c * 8 + lr) * 512 + k0 + lcs], &LDS[buf][1][c * 512]);
        }
    };

    f32x4 acc[4][4] = {};
    stage(0, 0);
    for (int s = 0; s < 8; ++s) {
        if (s < 7) stage((s + 1) & 1, (s + 1) * 64);
        __builtin_amdgcn_sched_barrier(0);
        if (s < 7) { asm volatile("s_waitcnt vmcnt(8)" ::: "memory"); }
        else       { asm volatile("s_waitcnt vmcnt(0)" ::: "memory"); }
        __builtin_amdgcn_sched_barrier(0);
        __builtin_amdgcn_s_barrier();
        __builtin_amdgcn_sched_barrier(0);   // ds_reads must stay AFTER the barrier
        const unsigned short* As = &LDS[s & 1][0][0];
        const unsigned short* Ws = &LDS[s & 1][1][0];
#pragma unroll
        for (int ks = 0; ks < 2; ++ks) {
            bf16x8 a[4], b[4];
            const int colsw = (ks * 32 + g * 8) ^ ((li & 7) << 3);
#pragma unroll
            for (int m = 0; m < 4; ++m)
                a[m] = *reinterpret_cast<const bf16x8*>(&As[(wr * 64 + m * 16 + li) * 64 + colsw]);
#pragma unroll
            for (int nn = 0; nn < 4; ++nn)
                b[nn] = *reinterpret_cast<const bf16x8*>(&Ws[(wc * 64 + nn * 16 + li) * 64 + colsw]);
            __builtin_amdgcn_s_setprio(1);
#pragma unroll
            for (int m = 0; m < 4; ++m)
#pragma unroll
                for (int nn = 0; nn < 4; ++nn)
                    acc[m][nn] = __builtin_amdgcn_mfma_f32_16x16x32_bf16(a[m], b[nn], acc[m][nn], 0, 0, 0);
            __builtin_amdgcn_s_setprio(0);
        }
        __builtin_amdgcn_sched_barrier(0);
        __builtin_amdgcn_s_barrier();
        __builtin_amdgcn_sched_barrier(0);
    }

    // Epilogue scalars (after vmcnt(0); compiler-managed waits)
    float bias_[4] = {0.f, 0.f, 0.f, 0.f}, pu_[4] = {0.f, 0.f, 0.f, 0.f}, pv_[4] = {0.f, 0.f, 0.f, 0.f};
    if (mode != 3) {
#pragma unroll
        for (int nn = 0; nn < 4; ++nn) {
            int gn = n0 + wc * 64 + nn * 16 + li;
            bias_[nn] = bias[gn];
            if (mode == 0) { pu_[nn] = pbu[gn]; pv_[nn] = pbv[gn]; }
        }
    }

    // ---- LDS-staged coalesced epilogue: Ct is a [128][136] bf16 tile ----
    unsigned short* Ct = &LDS[0][0][0];
    const int rrow = tid >> 4, rcol = (tid & 15) * 8;
    const float QS = 0.125f * 1.4426950408889634f;   // 1/8 * log2(e)

    if (mode == 2) {
        // transposed: rows = local d, cols = local t (packed 4-short writes)
#pragma unroll
        for (int m = 0; m < 4; ++m)
#pragma unroll
            for (int nn = 0; nn < 4; ++nn) {
                ushort4 pk;
                pk.x = f2b(acc[m][nn][0] + bias_[nn]);
                pk.y = f2b(acc[m][nn][1] + bias_[nn]);
                pk.z = f2b(acc[m][nn][2] + bias_[nn]);
                pk.w = f2b(acc[m][nn][3] + bias_[nn]);
                *reinterpret_cast<ushort4*>(&Ct[(wc * 64 + nn * 16 + li) * 136 + wr * 64 + m * 16 + g * 4]) = pk;
            }
        __syncthreads();
#pragma unroll
        for (int ps = 0; ps < 8; ++ps) {
            int rowd = ps * 16 + rrow;
            int gn = n0 + rowd, gm = m0 + rcol;
            int hh = gn >> 6, d = gn & 63, bb = gm >> 9, t = gm & 511;
            *reinterpret_cast<bf16x8*>(&vT[((long)(bb * 8 + hh) * 64 + d) * 512 + t]) =
                *reinterpret_cast<const bf16x8*>(&Ct[rowd * 136 + rcol]);
        }
    } else if (mode != 0) {
        // modes 1,3: row-major (bias_=0 for mode 3)
#pragma unroll
        for (int m = 0; m < 4; ++m)
#pragma unroll
            for (int nn = 0; nn < 4; ++nn)
#pragma unroll
                for (int r = 0; r < 4; ++r)
                    Ct[(wr * 64 + m * 16 + g * 4 + r) * 136 + wc * 64 + nn * 16 + li] =
                        f2b(acc[m][nn][r] + bias_[nn]);
        __syncthreads();
#pragma unroll
        for (int ps = 0; ps < 8; ++ps) {
            int row = ps * 16 + rrow;
            int gm = m0 + row, gn = n0 + rcol;
            bf16x8 v = *reinterpret_cast<const bf16x8*>(&Ct[row * 136 + rcol]);
            if (mode == 1) {
                int bb = gm >> 9, t = gm & 511, hh = gn >> 6, d = gn & 63;
                *reinterpret_cast<bf16x8*>(&kk[((long)(bb * 8 + hh) * 512 + t) * 64 + d]) = v;
            } else if (gm < M) {
                int bb = gm / 1023, j = gm - bb * 1023;
                int hh = gn >> 6, d = gn & 63;
                *reinterpret_cast<bf16x8*>(&pout[((long)(bb * 8 + hh) * 1024 + j) * 64 + d]) = v;
            }
        }
    } else {
        // mode 0: two passes (qu with pbu, qv with pbv), pre-scaled by QS
#pragma unroll
        for (int m = 0; m < 4; ++m)
#pragma unroll
            for (int nn = 0; nn < 4; ++nn)
#pragma unroll
                for (int r = 0; r < 4; ++r)
                    Ct[(wr * 64 + m * 16 + g * 4 + r) * 136 + wc * 64 + nn * 16 + li] =
                        f2b((acc[m][nn][r] + bias_[nn] + pu_[nn]) * QS);
        __syncthreads();
#pragma unroll
        for (int ps = 0; ps < 8; ++ps) {
            int row = ps * 16 + rrow;
            int gm = m0 + row, gn = n0 + rcol;
            int bb = gm >> 9, t = gm & 511, hh = gn >> 6, d = gn & 63;
            *reinterpret_cast<bf16x8*>(&qu[((long)(bb * 8 + hh) * 512 + t) * 64 + d]) =
                *reinterpret_cast<const bf16x8*>(&Ct[row * 136 + rcol]);
        }
        __syncthreads();
#pragma unroll
        for (int m = 0; m < 4; ++m)
#pragma unroll
            for (int nn = 0; nn < 4; ++nn)
#pragma unroll
                for (int r = 0; r < 4; ++r)
                    Ct[(wr * 64 + m * 16 + g * 4 + r) * 136 + wc * 64 + nn * 16 + li] =
                        f2b((acc[m][nn][r] + bias_[nn] + pv_[nn]) * QS);
        __syncthreads();
#pragma unroll
        for (int ps = 0; ps < 8; ++ps) {
            int row = ps * 16 + rrow;
            int gm = m0 + row, gn = n0 + rcol;
            int bb = gm >> 9, t = gm & 511, hh = gn >> 6, d = gn & 63;
            *reinterpret_cast<bf16x8*>(&qv[((long)(bb * 8 + hh) * 512 + t) * 64 + d]) =
                *reinterpret_cast<const bf16x8*>(&Ct[row * 136 + rcol]);
        }
    }
}

// Fused attention v5: QBLK=128, 8 waves (512 thr), 512 blocks. Per-wave math
// identical to v4 (16 q-rows/wave, 80-wide BD window, in-register shfl diagonal
// gather, exp2 softmax, deferred sum). Staging per q-row halves vs v4.
__global__ __launch_bounds__(512)
void attn_fused(const unsigned short* __restrict__ qu, const unsigned short* __restrict__ qv,
                const unsigned short* __restrict__ kk, const unsigned short* __restrict__ vT,
                const unsigned short* __restrict__ p, float* __restrict__ out)
{
    __shared__ unsigned short Ks[64][64];    // XOR-swizzled: col ^ ((row&7)<<3)
    __shared__ unsigned short Vs[64][64];
    __shared__ unsigned short Pw[192][64];
    __shared__ unsigned short UN[8][16][64]; // per-wave P strip, swizzled
    const int tid = threadIdx.x, lane = tid & 63, w = tid >> 6;   // w 0..7
    const int g = lane >> 4, li = lane & 15;
    const int n = blockIdx.x;            // 0..511, XCD-swizzled
    const int xcd = n & 7, rr = n >> 3;
    const int j = rr & 15, ti = rr >> 4; // ti 0..3
    const int bh = xcd * 16 + j;
    const int bb = bh >> 3, hh = bh & 7;
    const int t0 = ti * 128;
    const int wo = 112 - w * 16;         // wave's offset into the 192-row p window

    bf16x8 aq[2], av[2];
    const int trow = t0 + w * 16 + li;
#pragma unroll
    for (int ks = 0; ks < 2; ++ks) {
        aq[ks] = *reinterpret_cast<const bf16x8*>(&qu[((long)bh * 512 + trow) * 64 + ks * 32 + g * 8]);
        av[ks] = *reinterpret_cast<const bf16x8*>(&qv[((long)bh * 512 + trow) * 64 + ks * 32 + g * 8]);
    }

    bf16x8 kreg, vreg, preg[3];
    const int srow = tid >> 3, scol8 = (tid & 7) * 8;    // 512 threads -> 64 rows x 64 cols
    const int scolsw = scol8 ^ ((srow & 7) << 3);        // swizzled LDS col
    auto load_tile = [&](int s0) {
        const int pwb = 384 + s0 - t0;                   // in [0, 832]
        kreg = *reinterpret_cast<const bf16x8*>(&kk[((long)bh * 512 + s0 + srow) * 64 + scol8]);
        vreg = *reinterpret_cast<const bf16x8*>(&vT[((long)bh * 64 + srow) * 512 + s0 + scol8]);
#pragma unroll
        for (int i = 0; i < 3; ++i)
            preg[i] = *reinterpret_cast<const bf16x8*>(&p[((long)bh * 1024 + pwb + srow + i * 64) * 64 + scol8]);
    };

    f32x4 O[4] = {};
    float lrow[4] = {0.f, 0.f, 0.f, 0.f};

    load_tile(0);
    for (int s0 = 0; s0 < 512; s0 += 64) {
        *reinterpret_cast<bf16x8*>(&Ks[srow][scolsw]) = kreg;
        *reinterpret_cast<bf16x8*>(&Vs[srow][scolsw]) = vreg;
#pragma unroll
        for (int i = 0; i < 3; ++i)
            *reinterpret_cast<bf16x8*>(&Pw[srow + i * 64][scolsw]) = preg[i];
        __syncthreads();
        if (s0 < 448) load_tile(s0 + 64);   // prefetch next tile into regs

        // QK^T + BD (B-fragments from swizzled LDS)
        f32x4 S[4] = {};
        f32x4 bd[5] = {};
        __builtin_amdgcn_s_setprio(1);
#pragma unroll
        for (int ks = 0; ks < 2; ++ks) {
            const int colsw = (ks * 32 + g * 8) ^ ((li & 7) << 3);
#pragma unroll
            for (int f = 0; f < 4; ++f) {
                bf16x8 bf = *reinterpret_cast<const bf16x8*>(&Ks[f * 16 + li][colsw]);
                S[f] = __builtin_amdgcn_mfma_f32_16x16x32_bf16(aq[ks], bf, S[f], 0, 0, 0);
            }
#pragma unroll
            for (int fb = 0; fb < 5; ++fb) {
                bf16x8 bf = *reinterpret_cast<const bf16x8*>(&Pw[wo + fb * 16 + li][colsw]);
                bd[fb] = __builtin_amdgcn_mfma_f32_16x16x32_bf16(av[ks], bf, bd[fb], 0, 0, 0);
            }
        }
        __builtin_amdgcn_s_setprio(0);
        // diagonal rel-shift gather in-register: S[t,s] += BD[t, s-t+15]
#pragma unroll
        for (int r = 0; r < 4; ++r) {
            const int tt = g * 4 + r;
            const int sh = 15 - tt;
            const int srcl = (lane & 48) | ((li + sh) & 15);
            const bool wrap = (li + sh) >= 16;
            float sv[5];
#pragma unroll
            for (int q = 0; q < 5; ++q) sv[q] = __shfl(bd[q][r], srcl, 64);
#pragma unroll
            for (int f = 0; f < 4; ++f) {
                float pv = __builtin_exp2f(S[f][r] + (wrap ? sv[f + 1] : sv[f]));
                S[f][r] = pv;
                lrow[r] += pv;
            }
        }
        // P -> per-wave LDS strip (swizzled transpose to A-fragment layout)
#pragma unroll
        for (int f = 0; f < 4; ++f)
#pragma unroll
            for (int r = 0; r < 4; ++r) {
                int tt = g * 4 + r;
                UN[w][tt][(f * 16 + li) ^ ((tt & 7) << 3)] = f2b(S[f][r]);
            }
        // PV
        __builtin_amdgcn_s_setprio(1);
#pragma unroll
        for (int ks = 0; ks < 2; ++ks) {
            const int colsw = (ks * 32 + g * 8) ^ ((li & 7) << 3);
            bf16x8 pa = *reinterpret_cast<const bf16x8*>(&UN[w][li][colsw]);
#pragma unroll
            for (int fd = 0; fd < 4; ++fd) {
                bf16x8 vb = *reinterpret_cast<const bf16x8*>(&Vs[fd * 16 + li][colsw]);
                O[fd] = __builtin_amdgcn_mfma_f32_16x16x32_bf16(pa, vb, O[fd], 0, 0, 0);
            }
        }
        __builtin_amdgcn_s_setprio(0);
        __syncthreads();
    }
    // final row-sum reduce across the 16 lanes of each group
#pragma unroll
    for (int r = 0; r < 4; ++r) {
#pragma unroll
        for (int msk = 1; msk < 16; msk <<= 1)
            lrow[r] += __shfl_xor(lrow[r], msk);
    }
#pragma unroll
    for (int fd = 0; fd < 4; ++fd) {
#pragma unroll
        for (int r = 0; r < 4; ++r) {
            int t = t0 + w * 16 + g * 4 + r;
            int d = fd * 16 + li;
            out[((long)(bb * 512 + t)) * 512 + hh * 64 + d] = O[fd][r] / lrow[r];
        }
    }
}

extern "C" void kernel_launch(void* const* d_in, const int* in_sizes, int n_in,
                              void* d_out, int out_size, void* d_ws, size_t ws_size,
                              hipStream_t stream)
{
    const float* x   = (const float*)d_in[0];
    const float* pe  = (const float*)d_in[1];
    const float* Wq  = (const float*)d_in[2];
    const float* bq  = (const float*)d_in[3];
    const float* Wk  = (const float*)d_in[4];
    const float* bk  = (const float*)d_in[5];
    const float* Wv  = (const float*)d_in[6];
    const float* bv  = (const float*)d_in[7];
    const float* Wp  = (const float*)d_in[8];
    const float* pbu = (const float*)d_in[9];
    const float* pbv = (const float*)d_in[10];
    float* out = (float*)d_out;

    unsigned short* qu = (unsigned short*)d_ws;                  // [BH][512][64]
    unsigned short* qv = qu + (size_t)BH_ * 512 * 64;
    unsigned short* kk = qv + (size_t)BH_ * 512 * 64;
    unsigned short* vT = kk + (size_t)BH_ * 512 * 64;            // [BH][64][512]
    unsigned short* p  = vT + (size_t)BH_ * 512 * 64;            // [BH][1024][64]
    unsigned short* xb = p  + (size_t)BH_ * 1024 * 64;           // [8192][512]
    unsigned short* pb = xb + (size_t)NX_;                       // [16*1023][512]
    unsigned short* wb = pb + (size_t)NPE_;                      // [4*512][512]

    dim3 blk(256);
    convert_bf16<<<dim3(6656), blk, 0, stream>>>(x, pe, Wq, Wk, Wv, Wp, xb, pb, wb, p);
    proj_all<<<dim3(1280), blk, 0, stream>>>(xb, pb, wb, bq, bk, bv, pbu, pbv, qu, qv, kk, vT, p);
    attn_fused<<<dim3(512), dim3(512), 0, stream>>>(qu, qv, kk, vT, p, out);
}